// Round 1
// baseline (1989.860 us; speedup 1.0000x reference)
//
#include <hip/hip_runtime.h>
#include <math.h>

#define N_NODES 50000
#define N_EDGES 800000
#define F_IN 64
#define D 128
#define NLAYER 3
#define B_GRAPHS 8

__device__ __forceinline__ float gelu_exact(float x) {
    return 0.5f * x * (1.0f + erff(x * 0.7071067811865476f));
}

// 128-thread (2-wave) block sum, result broadcast to all threads
__device__ __forceinline__ float block_reduce_sum_128(float v, float* sbuf) {
    #pragma unroll
    for (int o = 32; o >= 1; o >>= 1) v += __shfl_down(v, o);
    if ((threadIdx.x & 63) == 0) sbuf[threadIdx.x >> 6] = v;
    __syncthreads();
    float r = sbuf[0] + sbuf[1];
    __syncthreads();
    return r;
}

__global__ void zero_kernel(float* __restrict__ p, int n) {
    int i = blockIdx.x * blockDim.x + threadIdx.x;
    int stride = gridDim.x * blockDim.x;
    for (; i < n; i += stride) p[i] = 0.f;
}

__global__ void degree_kernel(const int* __restrict__ dst, float* __restrict__ deg) {
    int e = blockIdx.x * blockDim.x + threadIdx.x;
    if (e < N_EDGES) atomicAdd(&deg[dst[e]], 1.0f);
}

// h = gelu(ln(x @ w_in + b_in));  one node per 128-thread block
__global__ void input_proj_kernel(const float* __restrict__ x, const float* __restrict__ w,
                                  const float* __restrict__ b, const float* __restrict__ g,
                                  const float* __restrict__ beta, float* __restrict__ h) {
    __shared__ float xs[F_IN];
    __shared__ float sbuf[2];
    int n = blockIdx.x;
    int d = threadIdx.x;
    if (d < F_IN) xs[d] = x[n * F_IN + d];
    __syncthreads();
    float acc = b[d];
    #pragma unroll 8
    for (int k = 0; k < F_IN; ++k) acc += xs[k] * w[k * D + d];
    float mean = block_reduce_sum_128(acc, sbuf) * (1.0f / D);
    float c = acc - mean;
    float var = block_reduce_sum_128(c * c, sbuf) * (1.0f / D);
    float y = c * rsqrtf(var + 1e-5f) * g[d] + beta[d];
    h[n * D + d] = gelu_exact(y);
}

// agg[dst] += h[src]; 2 edges per 256-thread block, dim per thread
__global__ void scatter_kernel(const int* __restrict__ src, const int* __restrict__ dst,
                               const float* __restrict__ h, float* __restrict__ agg) {
    int e = blockIdx.x * 2 + (threadIdx.x >> 7);
    int d = threadIdx.x & 127;
    if (e < N_EDGES) {
        int s = src[e], t = dst[e];
        atomicAdd(&agg[t * D + d], h[s * D + d]);
    }
}

// out = [h, agg/deg] @ W + b; gelu; ln1; ln2; optional gelu+residual
__global__ void gnn_layer_kernel(const float* __restrict__ agg, const float* __restrict__ deg,
                                 const float* __restrict__ W, const float* __restrict__ bias,
                                 const float* __restrict__ ln1g, const float* __restrict__ ln1b,
                                 const float* __restrict__ ln2g, const float* __restrict__ ln2b,
                                 float* __restrict__ h, int residual) {
    __shared__ float cat[2 * D];
    __shared__ float sbuf[2];
    int n = blockIdx.x;
    int d = threadIdx.x;
    float hold = h[n * D + d];
    cat[d] = hold;
    float dg = fmaxf(deg[n], 1.0f);
    cat[D + d] = agg[n * D + d] / dg;
    __syncthreads();
    float acc = bias[d];
    #pragma unroll 8
    for (int k = 0; k < 2 * D; ++k) acc += cat[k] * W[k * D + d];
    float x1 = gelu_exact(acc);
    float m1 = block_reduce_sum_128(x1, sbuf) * (1.0f / D);
    float c1 = x1 - m1;
    float v1 = block_reduce_sum_128(c1 * c1, sbuf) * (1.0f / D);
    float y1 = c1 * rsqrtf(v1 + 1e-5f) * ln1g[d] + ln1b[d];
    float m2 = block_reduce_sum_128(y1, sbuf) * (1.0f / D);
    float c2 = y1 - m2;
    float v2 = block_reduce_sum_128(c2 * c2, sbuf) * (1.0f / D);
    float y2 = c2 * rsqrtf(v2 + 1e-5f) * ln2g[d] + ln2b[d];
    h[n * D + d] = residual ? (gelu_exact(y2) + hold) : y2;
}

// logits[n] = tanh(h@w1 + b1) . w2 + b2
__global__ void gate_kernel(const float* __restrict__ h, const float* __restrict__ w1,
                            const float* __restrict__ b1, const float* __restrict__ w2,
                            const float* __restrict__ b2, float* __restrict__ logits) {
    __shared__ float hs[D];
    __shared__ float sbuf[2];
    int n = blockIdx.x, d = threadIdx.x;
    hs[d] = h[n * D + d];
    __syncthreads();
    float acc = b1[d];
    #pragma unroll 8
    for (int k = 0; k < D; ++k) acc += hs[k] * w1[k * D + d];
    float t = tanhf(acc);
    float s = block_reduce_sum_128(t * w2[d], sbuf);
    if (d == 0) logits[n] = s + b2[0];
}

// single block: global max + sum-of-exp over N logits; also zeroes pooled (1024 elems)
__global__ void softmax_stats_kernel(const float* __restrict__ logits, float* __restrict__ stats,
                                     float* __restrict__ pooled) {
    __shared__ float sbuf[16];
    int tid = threadIdx.x;
    pooled[tid] = 0.f;  // blockDim == 1024 == B_GRAPHS * D
    float mx = -INFINITY;
    for (int i = tid; i < N_NODES; i += 1024) mx = fmaxf(mx, logits[i]);
    #pragma unroll
    for (int o = 32; o >= 1; o >>= 1) mx = fmaxf(mx, __shfl_down(mx, o));
    if ((tid & 63) == 0) sbuf[tid >> 6] = mx;
    __syncthreads();
    if (tid == 0) {
        float m = sbuf[0];
        for (int w = 1; w < 16; ++w) m = fmaxf(m, sbuf[w]);
        sbuf[0] = m;
    }
    __syncthreads();
    mx = sbuf[0];
    __syncthreads();
    float sum = 0.f;
    for (int i = tid; i < N_NODES; i += 1024) sum += expf(logits[i] - mx);
    #pragma unroll
    for (int o = 32; o >= 1; o >>= 1) sum += __shfl_down(sum, o);
    if ((tid & 63) == 0) sbuf[tid >> 6] = sum;
    __syncthreads();
    if (tid == 0) {
        float s = 0.f;
        for (int w = 0; w < 16; ++w) s += sbuf[w];
        stats[0] = mx;
        stats[1] = 1.0f / s;
    }
}

// gate[n] = exp(logit-max)*invsum; pooled[batch] += h*gate (batch sorted -> run-flush)
#define POOL_CHUNK 128
__global__ void gate_pool_kernel(const float* __restrict__ h, const float* __restrict__ logits,
                                 const float* __restrict__ stats, const int* __restrict__ batch,
                                 float* __restrict__ gate_out, float* __restrict__ pooled) {
    __shared__ float gs[POOL_CHUNK];
    __shared__ int bs[POOL_CHUNK];
    int n0 = blockIdx.x * POOL_CHUNK;
    int d = threadIdx.x;
    float mx = stats[0], inv = stats[1];
    int nj = n0 + d;
    if (nj < N_NODES) {
        float gv = expf(logits[nj] - mx) * inv;
        gs[d] = gv;
        bs[d] = batch[nj];
        gate_out[nj] = gv;
    }
    __syncthreads();
    int count = min(POOL_CHUNK, N_NODES - n0);
    float acc = 0.f;
    int cur = bs[0];
    for (int t = 0; t < count; ++t) {
        int bn = bs[t];
        if (bn != cur) { atomicAdd(&pooled[cur * D + d], acc); acc = 0.f; cur = bn; }
        acc += h[(size_t)(n0 + t) * D + d] * gs[t];
    }
    atomicAdd(&pooled[cur * D + d], acc);
}

__global__ void out_proj_kernel(const float* __restrict__ pooled, const float* __restrict__ w,
                                const float* __restrict__ b, const float* __restrict__ g,
                                const float* __restrict__ beta, float* __restrict__ emb) {
    __shared__ float ps[D];
    __shared__ float sbuf[2];
    int bg = blockIdx.x, d = threadIdx.x;
    ps[d] = pooled[bg * D + d];
    __syncthreads();
    float acc = b[d];
    #pragma unroll 8
    for (int k = 0; k < D; ++k) acc += ps[k] * w[k * D + d];
    float m = block_reduce_sum_128(acc, sbuf) * (1.0f / D);
    float c = acc - m;
    float v = block_reduce_sum_128(c * c, sbuf) * (1.0f / D);
    float y = c * rsqrtf(v + 1e-5f) * g[d] + beta[d];
    emb[bg * D + d] = gelu_exact(y);
}

extern "C" void kernel_launch(void* const* d_in, const int* in_sizes, int n_in,
                              void* d_out, int out_size, void* d_ws, size_t ws_size,
                              hipStream_t stream) {
    const float* x        = (const float*)d_in[0];
    const int*   edge     = (const int*)d_in[1];
    const int*   batch    = (const int*)d_in[2];
    const float* w_in     = (const float*)d_in[3];
    const float* b_in     = (const float*)d_in[4];
    const float* ln_in_g  = (const float*)d_in[5];
    const float* ln_in_b  = (const float*)d_in[6];
    const float* gnn_w    = (const float*)d_in[7];
    const float* gnn_b    = (const float*)d_in[8];
    const float* gnn_ln_g = (const float*)d_in[9];
    const float* gnn_ln_b = (const float*)d_in[10];
    const float* norm_g   = (const float*)d_in[11];
    const float* norm_b   = (const float*)d_in[12];
    const float* gate_w1  = (const float*)d_in[13];
    const float* gate_b1  = (const float*)d_in[14];
    const float* gate_w2  = (const float*)d_in[15];
    const float* gate_b2  = (const float*)d_in[16];
    const float* out_w    = (const float*)d_in[17];
    const float* out_b    = (const float*)d_in[18];
    const float* out_ln_g = (const float*)d_in[19];
    const float* out_ln_b = (const float*)d_in[20];

    const int* src = edge;             // edge_index[0]
    const int* dst = edge + N_EDGES;   // edge_index[1]

    float* out      = (float*)d_out;
    float* emb      = out;                               // (8,128)
    float* h        = out + B_GRAPHS * D;                // (N,128)
    float* gate_out = h + (size_t)N_NODES * D;           // (N,)

    float* ws     = (float*)d_ws;
    float* deg    = ws;                                  // N
    float* logits = ws + N_NODES;                        // N
    float* agg    = ws + 2 * N_NODES;                    // N*128
    float* pooled = agg + (size_t)N_NODES * D;           // 1024
    float* stats  = pooled + B_GRAPHS * D;               // 2

    zero_kernel<<<256, 256, 0, stream>>>(deg, N_NODES);
    degree_kernel<<<(N_EDGES + 255) / 256, 256, 0, stream>>>(dst, deg);
    input_proj_kernel<<<N_NODES, D, 0, stream>>>(x, w_in, b_in, ln_in_g, ln_in_b, h);

    for (int i = 0; i < NLAYER; ++i) {
        zero_kernel<<<2048, 256, 0, stream>>>(agg, N_NODES * D);
        scatter_kernel<<<(N_EDGES + 1) / 2, 256, 0, stream>>>(src, dst, h, agg);
        gnn_layer_kernel<<<N_NODES, D, 0, stream>>>(
            agg, deg,
            gnn_w + (size_t)i * 2 * D * D, gnn_b + i * D,
            gnn_ln_g + i * D, gnn_ln_b + i * D,
            norm_g + i * D, norm_b + i * D,
            h, (i < NLAYER - 1) ? 1 : 0);
    }

    gate_kernel<<<N_NODES, D, 0, stream>>>(h, gate_w1, gate_b1, gate_w2, gate_b2, logits);
    softmax_stats_kernel<<<1, 1024, 0, stream>>>(logits, stats, pooled);
    gate_pool_kernel<<<(N_NODES + POOL_CHUNK - 1) / POOL_CHUNK, D, 0, stream>>>(
        h, logits, stats, batch, gate_out, pooled);
    out_proj_kernel<<<B_GRAPHS, D, 0, stream>>>(pooled, out_w, out_b, out_ln_g, out_ln_b, emb);
}

// Round 3
// 926.358 us; speedup vs baseline: 2.1480x; 2.1480x over previous
//
#include <hip/hip_runtime.h>
#include <math.h>

#define N_NODES 50000
#define N_EDGES 800000
#define F_IN 64
#define D 128
#define NLAYER 3
#define B_GRAPHS 8
#define G 8               // nodes per block in tiled kernels (50000 % 8 == 0 -> 6250 blocks)

__device__ __forceinline__ float gelu_exact(float x) {
    return 0.5f * x * (1.0f + erff(x * 0.7071067811865476f));
}

// ---------------- CSR build ----------------

__global__ void zero_int_kernel(int* __restrict__ p, int n) {
    int i = blockIdx.x * blockDim.x + threadIdx.x;
    int stride = gridDim.x * blockDim.x;
    for (; i < n; i += stride) p[i] = 0;
}

__global__ void degree_kernel(const int* __restrict__ dst, int* __restrict__ deg) {
    int e = blockIdx.x * blockDim.x + threadIdx.x;
    if (e < N_EDGES) atomicAdd(&deg[dst[e]], 1);
}

// single block, 1024 threads: exclusive scan of deg -> row_ptr (and cursor copy)
__global__ void scan_kernel(const int* __restrict__ deg, int* __restrict__ row_ptr,
                            int* __restrict__ cursor) {
    __shared__ int wsum[16];
    __shared__ int carry_s;
    int tid = threadIdx.x;
    int lane = tid & 63, wave = tid >> 6;
    if (tid == 0) carry_s = 0;
    __syncthreads();
    for (int base = 0; base < N_NODES; base += 1024) {
        int i = base + tid;
        int v = (i < N_NODES) ? deg[i] : 0;
        int x = v;
        #pragma unroll
        for (int o = 1; o < 64; o <<= 1) {
            int nb = __shfl_up(x, o);
            if (lane >= o) x += nb;
        }
        if (lane == 63) wsum[wave] = x;
        __syncthreads();
        if (tid == 0) {
            int run = carry_s;
            for (int w = 0; w < 16; ++w) { int t = wsum[w]; wsum[w] = run; run += t; }
            carry_s = run;
        }
        __syncthreads();
        int excl = wsum[wave] + x - v;
        if (i < N_NODES) { row_ptr[i] = excl; cursor[i] = excl; }
        __syncthreads();
    }
    if (tid == 0) row_ptr[N_NODES] = carry_s;
}

__global__ void fill_kernel(const int* __restrict__ src, const int* __restrict__ dst,
                            int* __restrict__ cursor, int* __restrict__ csr) {
    int e = blockIdx.x * blockDim.x + threadIdx.x;
    if (e < N_EDGES) {
        int t = dst[e];
        int pos = atomicAdd(&cursor[t], 1);
        csr[pos] = src[e];
    }
}

// ---------------- tiled node kernels ----------------
// mapping: 256 threads; d = tid&127; half = tid>>7; thread owns nodes g0..g0+3, g0 = half*4

// h = gelu(ln(x @ w_in + b_in))
__global__ __launch_bounds__(256) void input_proj_tiled(
        const float* __restrict__ x, const float* __restrict__ w,
        const float* __restrict__ b, const float* __restrict__ gam,
        const float* __restrict__ bet, float* __restrict__ h) {
    __shared__ float xs[G][F_IN];
    __shared__ float red[4][8];
    int n0 = blockIdx.x * G;
    int tid = threadIdx.x;
    int d = tid & 127, half = tid >> 7, g0 = half * 4;
    int lane = tid & 63, wave = tid >> 6;

    for (int i = tid; i < G * F_IN; i += 256) {
        int g = i >> 6, k = i & 63;
        xs[g][k] = x[(size_t)(n0 + g) * F_IN + k];
    }
    __syncthreads();

    float bd = b[d];
    float acc[4] = {bd, bd, bd, bd};
    #pragma unroll 2
    for (int k0 = 0; k0 < F_IN; k0 += 4) {
        float w0 = w[(k0 + 0) * D + d];
        float w1 = w[(k0 + 1) * D + d];
        float w2v = w[(k0 + 2) * D + d];
        float w3 = w[(k0 + 3) * D + d];
        #pragma unroll
        for (int j = 0; j < 4; ++j) {
            float4 c = *(const float4*)&xs[g0 + j][k0];
            acc[j] += c.x * w0 + c.y * w1 + c.z * w2v + c.w * w3;
        }
    }
    // LN: sum + sumsq in one pass
    float s[4], q[4];
    #pragma unroll
    for (int j = 0; j < 4; ++j) { s[j] = acc[j]; q[j] = acc[j] * acc[j]; }
    #pragma unroll
    for (int o = 32; o >= 1; o >>= 1)
        #pragma unroll
        for (int j = 0; j < 4; ++j) { s[j] += __shfl_down(s[j], o); q[j] += __shfl_down(q[j], o); }
    if (lane == 0)
        #pragma unroll
        for (int j = 0; j < 4; ++j) { red[wave][j] = s[j]; red[wave][4 + j] = q[j]; }
    __syncthreads();
    int w0i = half * 2, w1i = w0i + 1;
    float gd = gam[d], btd = bet[d];
    #pragma unroll
    for (int j = 0; j < 4; ++j) {
        float mean = (red[w0i][j] + red[w1i][j]) * (1.0f / D);
        float msq  = (red[w0i][4 + j] + red[w1i][4 + j]) * (1.0f / D);
        float var = msq - mean * mean;
        float y = (acc[j] - mean) * rsqrtf(var + 1e-5f) * gd + btd;
        h[(size_t)(n0 + g0 + j) * D + d] = gelu_exact(y);
    }
}

// fused: gather(mean-neighbor via CSR from h_in) + [h,agg]@W + gelu + LN1 + LN2 (+gelu+residual)
// h_in and h_out are DISTINCT buffers (ping-pong) -> no inter-block race.
__global__ __launch_bounds__(256) void gnn_layer_tiled(
        const float* __restrict__ h_in, float* __restrict__ h_out,
        const int* __restrict__ csr, const int* __restrict__ rp,
        const float* __restrict__ W, const float* __restrict__ bias,
        const float* __restrict__ ln1g, const float* __restrict__ ln1b,
        const float* __restrict__ ln2g, const float* __restrict__ ln2b,
        int residual) {
    __shared__ float cat[G][2 * D];   // 8 KB
    __shared__ float red[4][8];
    int n0 = blockIdx.x * G;
    int tid = threadIdx.x;
    int d = tid & 127, half = tid >> 7, g0 = half * 4;
    int lane = tid & 63, wave = tid >> 6;

    // load h rows (also residual) + gather neighbors, 4 nodes per half
    float hold[4];
    #pragma unroll
    for (int j = 0; j < 4; ++j) {
        int g = g0 + j;
        int n = n0 + g;
        float hv = h_in[(size_t)n * D + d];
        hold[j] = hv;
        cat[g][d] = hv;
        int beg = rp[n], end = rp[n + 1];
        float acc = 0.f;
        int e = beg;
        for (; e + 1 < end; e += 2) {
            int s0 = csr[e], s1 = csr[e + 1];
            acc += h_in[(size_t)s0 * D + d] + h_in[(size_t)s1 * D + d];
        }
        if (e < end) acc += h_in[(size_t)csr[e] * D + d];
        float inv = 1.0f / fmaxf((float)(end - beg), 1.0f);
        cat[g][D + d] = acc * inv;
    }
    __syncthreads();

    float bd = bias[d];
    float acc[4] = {bd, bd, bd, bd};
    #pragma unroll 2
    for (int k0 = 0; k0 < 2 * D; k0 += 4) {
        float wA = W[(k0 + 0) * D + d];
        float wB = W[(k0 + 1) * D + d];
        float wC = W[(k0 + 2) * D + d];
        float wD = W[(k0 + 3) * D + d];
        #pragma unroll
        for (int j = 0; j < 4; ++j) {
            float4 c = *(const float4*)&cat[g0 + j][k0];
            acc[j] += c.x * wA + c.y * wB + c.z * wC + c.w * wD;
        }
    }

    // gelu then LN1
    float x1[4];
    #pragma unroll
    for (int j = 0; j < 4; ++j) x1[j] = gelu_exact(acc[j]);

    float s[4], q[4];
    #pragma unroll
    for (int j = 0; j < 4; ++j) { s[j] = x1[j]; q[j] = x1[j] * x1[j]; }
    #pragma unroll
    for (int o = 32; o >= 1; o >>= 1)
        #pragma unroll
        for (int j = 0; j < 4; ++j) { s[j] += __shfl_down(s[j], o); q[j] += __shfl_down(q[j], o); }
    if (lane == 0)
        #pragma unroll
        for (int j = 0; j < 4; ++j) { red[wave][j] = s[j]; red[wave][4 + j] = q[j]; }
    __syncthreads();
    int w0i = half * 2, w1i = w0i + 1;
    float g1 = ln1g[d], b1 = ln1b[d];
    float y1[4];
    #pragma unroll
    for (int j = 0; j < 4; ++j) {
        float mean = (red[w0i][j] + red[w1i][j]) * (1.0f / D);
        float msq  = (red[w0i][4 + j] + red[w1i][4 + j]) * (1.0f / D);
        float var = msq - mean * mean;
        y1[j] = (x1[j] - mean) * rsqrtf(var + 1e-5f) * g1 + b1;
    }
    // LN2
    __syncthreads();
    #pragma unroll
    for (int j = 0; j < 4; ++j) { s[j] = y1[j]; q[j] = y1[j] * y1[j]; }
    #pragma unroll
    for (int o = 32; o >= 1; o >>= 1)
        #pragma unroll
        for (int j = 0; j < 4; ++j) { s[j] += __shfl_down(s[j], o); q[j] += __shfl_down(q[j], o); }
    if (lane == 0)
        #pragma unroll
        for (int j = 0; j < 4; ++j) { red[wave][j] = s[j]; red[wave][4 + j] = q[j]; }
    __syncthreads();
    float g2 = ln2g[d], b2 = ln2b[d];
    #pragma unroll
    for (int j = 0; j < 4; ++j) {
        float mean = (red[w0i][j] + red[w1i][j]) * (1.0f / D);
        float msq  = (red[w0i][4 + j] + red[w1i][4 + j]) * (1.0f / D);
        float var = msq - mean * mean;
        float y2 = (y1[j] - mean) * rsqrtf(var + 1e-5f) * g2 + b2;
        float outv = residual ? (gelu_exact(y2) + hold[j]) : y2;
        h_out[(size_t)(n0 + g0 + j) * D + d] = outv;
    }
}

// logits[n] = tanh(h@w1 + b1) . w2 + b2
__global__ __launch_bounds__(256) void gate_tiled(
        const float* __restrict__ h, const float* __restrict__ w1,
        const float* __restrict__ b1, const float* __restrict__ w2,
        const float* __restrict__ b2, float* __restrict__ logits) {
    __shared__ float hs[G][D];
    __shared__ float red[4][8];
    int n0 = blockIdx.x * G;
    int tid = threadIdx.x;
    int d = tid & 127, half = tid >> 7, g0 = half * 4;
    int lane = tid & 63, wave = tid >> 6;

    for (int i = tid; i < G * D; i += 256) {
        int g = i >> 7, k = i & 127;
        hs[g][k] = h[(size_t)(n0 + g) * D + k];
    }
    __syncthreads();

    float bd = b1[d];
    float acc[4] = {bd, bd, bd, bd};
    #pragma unroll 2
    for (int k0 = 0; k0 < D; k0 += 4) {
        float wA = w1[(k0 + 0) * D + d];
        float wB = w1[(k0 + 1) * D + d];
        float wC = w1[(k0 + 2) * D + d];
        float wD = w1[(k0 + 3) * D + d];
        #pragma unroll
        for (int j = 0; j < 4; ++j) {
            float4 c = *(const float4*)&hs[g0 + j][k0];
            acc[j] += c.x * wA + c.y * wB + c.z * wC + c.w * wD;
        }
    }
    float w2d = w2[d];
    float s[4];
    #pragma unroll
    for (int j = 0; j < 4; ++j) s[j] = tanhf(acc[j]) * w2d;
    #pragma unroll
    for (int o = 32; o >= 1; o >>= 1)
        #pragma unroll
        for (int j = 0; j < 4; ++j) s[j] += __shfl_down(s[j], o);
    if (lane == 0)
        #pragma unroll
        for (int j = 0; j < 4; ++j) red[wave][j] = s[j];
    __syncthreads();
    if ((tid & 127) == 0) {
        int w0i = half * 2, w1i = w0i + 1;
        float bb = b2[0];
        #pragma unroll
        for (int j = 0; j < 4; ++j)
            logits[n0 + g0 + j] = red[w0i][j] + red[w1i][j] + bb;
    }
}

// single block: global max + sum-of-exp over N logits; also zeroes pooled (1024 elems)
__global__ void softmax_stats_kernel(const float* __restrict__ logits, float* __restrict__ stats,
                                     float* __restrict__ pooled) {
    __shared__ float sbuf[16];
    int tid = threadIdx.x;
    pooled[tid] = 0.f;  // blockDim == 1024 == B_GRAPHS * D
    float mx = -INFINITY;
    for (int i = tid; i < N_NODES; i += 1024) mx = fmaxf(mx, logits[i]);
    #pragma unroll
    for (int o = 32; o >= 1; o >>= 1) mx = fmaxf(mx, __shfl_down(mx, o));
    if ((tid & 63) == 0) sbuf[tid >> 6] = mx;
    __syncthreads();
    if (tid == 0) {
        float m = sbuf[0];
        for (int w = 1; w < 16; ++w) m = fmaxf(m, sbuf[w]);
        sbuf[0] = m;
    }
    __syncthreads();
    mx = sbuf[0];
    __syncthreads();
    float sum = 0.f;
    for (int i = tid; i < N_NODES; i += 1024) sum += expf(logits[i] - mx);
    #pragma unroll
    for (int o = 32; o >= 1; o >>= 1) sum += __shfl_down(sum, o);
    if ((tid & 63) == 0) sbuf[tid >> 6] = sum;
    __syncthreads();
    if (tid == 0) {
        float s = 0.f;
        for (int w = 0; w < 16; ++w) s += sbuf[w];
        stats[0] = mx;
        stats[1] = 1.0f / s;
    }
}

// gate[n] = exp(logit-max)*invsum; pooled[batch] += h*gate (batch sorted -> run-flush)
#define POOL_CHUNK 128
__global__ void gate_pool_kernel(const float* __restrict__ h, const float* __restrict__ logits,
                                 const float* __restrict__ stats, const int* __restrict__ batch,
                                 float* __restrict__ gate_out, float* __restrict__ pooled) {
    __shared__ float gs[POOL_CHUNK];
    __shared__ int bs[POOL_CHUNK];
    int n0 = blockIdx.x * POOL_CHUNK;
    int d = threadIdx.x;
    float mx = stats[0], inv = stats[1];
    int nj = n0 + d;
    if (nj < N_NODES) {
        float gv = expf(logits[nj] - mx) * inv;
        gs[d] = gv;
        bs[d] = batch[nj];
        gate_out[nj] = gv;
    }
    __syncthreads();
    int count = min(POOL_CHUNK, N_NODES - n0);
    float acc = 0.f;
    int cur = bs[0];
    for (int t = 0; t < count; ++t) {
        int bn = bs[t];
        if (bn != cur) { atomicAdd(&pooled[cur * D + d], acc); acc = 0.f; cur = bn; }
        acc += h[(size_t)(n0 + t) * D + d] * gs[t];
    }
    atomicAdd(&pooled[cur * D + d], acc);
}

__global__ void out_proj_kernel(const float* __restrict__ pooled, const float* __restrict__ w,
                                const float* __restrict__ b, const float* __restrict__ g,
                                const float* __restrict__ beta, float* __restrict__ emb) {
    __shared__ float ps[D];
    __shared__ float sbuf[2];
    int bg = blockIdx.x, d = threadIdx.x;
    ps[d] = pooled[bg * D + d];
    __syncthreads();
    float acc = b[d];
    #pragma unroll 8
    for (int k = 0; k < D; ++k) acc += ps[k] * w[k * D + d];
    // block reduce (128 threads)
    float s = acc, q = acc * acc;
    #pragma unroll
    for (int o = 32; o >= 1; o >>= 1) { s += __shfl_down(s, o); q += __shfl_down(q, o); }
    if ((d & 63) == 0) { sbuf[d >> 6] = s; }
    __syncthreads();
    float fullsum = sbuf[0] + sbuf[1];
    __syncthreads();
    if ((d & 63) == 0) { sbuf[d >> 6] = q; }
    __syncthreads();
    float fullsq = sbuf[0] + sbuf[1];
    float m = fullsum * (1.0f / D);
    float var = fullsq * (1.0f / D) - m * m;
    float y = (acc - m) * rsqrtf(var + 1e-5f) * g[d] + beta[d];
    emb[bg * D + d] = gelu_exact(y);
}

extern "C" void kernel_launch(void* const* d_in, const int* in_sizes, int n_in,
                              void* d_out, int out_size, void* d_ws, size_t ws_size,
                              hipStream_t stream) {
    const float* x        = (const float*)d_in[0];
    const int*   edge     = (const int*)d_in[1];
    const int*   batch    = (const int*)d_in[2];
    const float* w_in     = (const float*)d_in[3];
    const float* b_in     = (const float*)d_in[4];
    const float* ln_in_g  = (const float*)d_in[5];
    const float* ln_in_b  = (const float*)d_in[6];
    const float* gnn_w    = (const float*)d_in[7];
    const float* gnn_b    = (const float*)d_in[8];
    const float* gnn_ln_g = (const float*)d_in[9];
    const float* gnn_ln_b = (const float*)d_in[10];
    const float* norm_g   = (const float*)d_in[11];
    const float* norm_b   = (const float*)d_in[12];
    const float* gate_w1  = (const float*)d_in[13];
    const float* gate_b1  = (const float*)d_in[14];
    const float* gate_w2  = (const float*)d_in[15];
    const float* gate_b2  = (const float*)d_in[16];
    const float* out_w    = (const float*)d_in[17];
    const float* out_b    = (const float*)d_in[18];
    const float* out_ln_g = (const float*)d_in[19];
    const float* out_ln_b = (const float*)d_in[20];

    const int* src = edge;             // edge_index[0]
    const int* dst = edge + N_EDGES;   // edge_index[1]

    float* out      = (float*)d_out;
    float* emb      = out;                               // (8,128)
    float* hA       = out + B_GRAPHS * D;                // (N,128) final h location
    float* gate_out = hA + (size_t)N_NODES * D;          // (N,)

    // workspace layout: hB first (N*D floats); CSR-build temporaries deg/cursor
    // are OVERLAID inside hB (they die before input_proj overwrites hB).
    float* hB      = (float*)d_ws;                       // N*D floats
    int*   deg_i   = (int*)d_ws;                         // N      (overlay, build phase only)
    int*   cursor  = (int*)d_ws + N_NODES;               // N+1    (overlay, build phase only)
    int*   row_ptr = (int*)(hB + (size_t)N_NODES * D);   // N+1
    int*   csr     = row_ptr + N_NODES + 1;              // E
    float* logits  = (float*)(csr + N_EDGES);            // N
    float* pooled  = logits + N_NODES;                   // 1024
    float* stats   = pooled + B_GRAPHS * D;              // 2

    // CSR build (deg/cursor live in the hB region; done before hB is written)
    zero_int_kernel<<<128, 256, 0, stream>>>(deg_i, N_NODES);
    degree_kernel<<<(N_EDGES + 255) / 256, 256, 0, stream>>>(dst, deg_i);
    scan_kernel<<<1, 1024, 0, stream>>>(deg_i, row_ptr, cursor);
    fill_kernel<<<(N_EDGES + 255) / 256, 256, 0, stream>>>(src, dst, cursor, csr);

    // input proj -> hB
    input_proj_tiled<<<N_NODES / G, 256, 0, stream>>>(x, w_in, b_in, ln_in_g, ln_in_b, hB);

    // ping-pong: hB -> hA -> hB -> hA  (final h lands in hA = d_out slice)
    const float* hin[3]  = {hB, hA, hB};
    float*       hout[3] = {hA, hB, hA};
    for (int i = 0; i < NLAYER; ++i) {
        gnn_layer_tiled<<<N_NODES / G, 256, 0, stream>>>(
            hin[i], hout[i], csr, row_ptr,
            gnn_w + (size_t)i * 2 * D * D, gnn_b + i * D,
            gnn_ln_g + i * D, gnn_ln_b + i * D,
            norm_g + i * D, norm_b + i * D,
            (i < NLAYER - 1) ? 1 : 0);
    }

    gate_tiled<<<N_NODES / G, 256, 0, stream>>>(hA, gate_w1, gate_b1, gate_w2, gate_b2, logits);
    softmax_stats_kernel<<<1, 1024, 0, stream>>>(logits, stats, pooled);
    gate_pool_kernel<<<(N_NODES + POOL_CHUNK - 1) / POOL_CHUNK, POOL_CHUNK, 0, stream>>>(
        hA, logits, stats, batch, gate_out, pooled);
    out_proj_kernel<<<B_GRAPHS, D, 0, stream>>>(pooled, out_w, out_b, out_ln_g, out_ln_b, emb);
}